// Round 10
// baseline (88.576 us; speedup 1.0000x reference)
//
#include <hip/hip_runtime.h>
#include <math.h>

// Problem constants: V=50257, H=2048, E=1024, L=4
#define LSTM_H 2048
#define LSTM_E 1024
#define LSTM_L 4
#define FOURH  8192

// Native clang vector type so __builtin_nontemporal_load accepts it.
typedef float f32x4 __attribute__((ext_vector_type(4)));

__device__ __forceinline__ float sigmoidf_(float x) {
    return 1.0f / (1.0f + __expf(-x));
}

__device__ __forceinline__ float wave_reduce(float s) {
    #pragma unroll
    for (int off = 32; off > 0; off >>= 1)
        s += __shfl_down(s, off, 64);
    return s;
}

// Regular cached dot (weights expected to be L3-resident across replays).
__device__ __forceinline__ float dot2048(const float* __restrict__ w,
                                         const float* __restrict__ v, int lane) {
    const float4* __restrict__ w4 = (const float4*)w;
    const float4* __restrict__ v4 = (const float4*)v;
    float s = 0.0f;
    #pragma unroll
    for (int t = 0; t < 8; ++t) {
        const int idx = lane + t * 64;
        float4 a = w4[idx];
        float4 b = v4[idx];
        s += a.x * b.x + a.y * b.y + a.z * b.z + a.w * b.w;
    }
    return s;
}

__device__ __forceinline__ float dot1024(const float* __restrict__ w,
                                         const float* __restrict__ v, int lane) {
    const float4* __restrict__ w4 = (const float4*)w;
    const float4* __restrict__ v4 = (const float4*)v;
    float s = 0.0f;
    #pragma unroll
    for (int t = 0; t < 4; ++t) {
        const int idx = lane + t * 64;
        float4 a = w4[idx];
        float4 b = v4[idx];
        s += a.x * b.x + a.y * b.y + a.z * b.z + a.w * b.w;
    }
    return s;
}

// Non-temporal weight stream (bulk of W_hh: single-use per replay; keep OUT of
// L3 so W_ih0/W_ihR/fc_W + a 16MB slice of W_hh stay LLC-resident).
__device__ __forceinline__ float dot2048_wnt(const float* __restrict__ w,
                                             const float* __restrict__ v, int lane) {
    const f32x4*  __restrict__ w4 = (const f32x4*)w;
    const float4* __restrict__ v4 = (const float4*)v;
    float s = 0.0f;
    #pragma unroll
    for (int t = 0; t < 8; ++t) {
        const int idx = lane + t * 64;
        f32x4  a = __builtin_nontemporal_load(w4 + idx);
        float4 b = v4[idx];
        s += a.x * b.x + a.y * b.y + a.z * b.z + a.w * b.w;
    }
    return s;
}

// ---------------- K1: all dependency-free work ----------------
// Blocks [0, 2048): unit-mode layer 0 — full gates + cell update for unit j.
//   W_ih0 row cached (L3-pinned set), W_hh0 row non-temporal.
// Blocks [2048, 5120): row-mode W_hh partials for layers 1..3, 2 CONSECUTIVE
//   rows per wave (16KB contiguous footprint, 2 streams/wave, v loaded once
//   per pair from L1/L2 — no LDS, no barrier). Last 2048 rows (16MB) cached.
__global__ __launch_bounds__(256)
void k1_parallel(const int*   __restrict__ token,
                 const float* __restrict__ hidden,  // [L,1,H]
                 const float* __restrict__ cell,    // [L,1,H]
                 const float* __restrict__ emb,     // [V,E]
                 const float* __restrict__ W_ih0,   // [4H,E]
                 const float* __restrict__ W_hh,    // [L,4H,H]
                 const float* __restrict__ b_ih,    // [L,4H]
                 const float* __restrict__ b_hh,    // [L,4H]
                 float* __restrict__ h_new,         // [L*H]
                 float* __restrict__ c_new,         // [L*H]
                 float* __restrict__ part)          // [3][4H]
{
    const int wave = threadIdx.x >> 6;
    const int lane = threadIdx.x & 63;

    if (blockIdx.x < 2048) {
        // ---- unit-mode: layer 0, unit j (r9-proven) ----
        const int j   = blockIdx.x;
        const int row = wave * LSTM_H + j;

        const float bias  = b_ih[row] + b_hh[row];
        const float c_in0 = cell[j];
        const float* xemb = emb + (size_t)(*token) * LSTM_E;

        float s = dot1024(W_ih0 + (size_t)row * LSTM_E, xemb, lane)
                + dot2048_wnt(W_hh + (size_t)row * LSTM_H, hidden, lane);
        s = wave_reduce(s);

        __shared__ float gsh[4];
        if (lane == 0) gsh[wave] = s + bias;
        __syncthreads();

        if (threadIdx.x == 0) {
            const float i_ = sigmoidf_(gsh[0]);
            const float f_ = sigmoidf_(gsh[1]);
            const float g_ = tanhf(gsh[2]);
            const float o_ = sigmoidf_(gsh[3]);
            const float c  = f_ * c_in0 + i_ * g_;
            c_new[j] = c;
            h_new[j] = o_ * tanhf(c);
        }
    } else {
        // ---- row-mode: W_hh partials, 2 consecutive rows per wave ----
        const int p     = (blockIdx.x - 2048) * 4 + wave;  // pair idx 0..12287
        const int r0    = 2 * p;                           // 0..24574 (even)
        const int lidx  = r0 >> 13;          // 0..2  -> layer lidx+1
        const int rowin = r0 & (FOURH - 1);  // row within the layer's [4H]

        const size_t brow0 = (size_t)(lidx + 1) * FOURH + rowin;
        const float bias0 = b_ih[brow0]     + b_hh[brow0];
        const float bias1 = b_ih[brow0 + 1] + b_hh[brow0 + 1];

        const float* w0 = W_hh + (size_t)(lidx + 1) * FOURH * LSTM_H
                                + (size_t)rowin * LSTM_H;
        const float* v  = hidden + (size_t)(lidx + 1) * LSTM_H;

        const float4* __restrict__ v4  = (const float4*)v;
        float s0 = 0.f, s1 = 0.f;

        // Last 2048 rows (16MB) stay CACHED (L3-resident across replays).
        if (r0 >= 24576 - 2048) {
            const float4* __restrict__ w40 = (const float4*)w0;
            const float4* __restrict__ w41 = w40 + (LSTM_H / 4);
            #pragma unroll
            for (int t = 0; t < 8; ++t) {
                const int idx = lane + t * 64;
                const float4 b  = v4[idx];
                const float4 a0 = w40[idx];
                const float4 a1 = w41[idx];
                s0 += a0.x * b.x + a0.y * b.y + a0.z * b.z + a0.w * b.w;
                s1 += a1.x * b.x + a1.y * b.y + a1.z * b.z + a1.w * b.w;
            }
        } else {
            const f32x4* __restrict__ w40 = (const f32x4*)w0;
            const f32x4* __restrict__ w41 = w40 + (LSTM_H / 4);
            #pragma unroll
            for (int t = 0; t < 8; ++t) {
                const int idx = lane + t * 64;
                const float4 b  = v4[idx];
                const f32x4  a0 = __builtin_nontemporal_load(w40 + idx);
                const f32x4  a1 = __builtin_nontemporal_load(w41 + idx);
                s0 += a0.x * b.x + a0.y * b.y + a0.z * b.z + a0.w * b.w;
                s1 += a1.x * b.x + a1.y * b.y + a1.z * b.z + a1.w * b.w;
            }
        }

        s0 = wave_reduce(s0);
        s1 = wave_reduce(s1);
        if (lane == 0) {
            part[(size_t)lidx * FOURH + rowin]     = s0 + bias0;
            part[(size_t)lidx * FOURH + rowin + 1] = s1 + bias1;
        }
    }
}

// ---------------- KB: sequential part of layer l (round-5 proven) ----------
// W_ihR reads stay CACHED — this is the stream we want L3-resident.
__global__ __launch_bounds__(256)
void kb_layer(const float* __restrict__ W_ih,   // [4H, H] (layer's W_ihR slice)
              const float* __restrict__ part_l, // [4H] W_hh part + biases
              const float* __restrict__ hx,     // [H] h_{l-1}
              const float* __restrict__ c_in,   // [H]
              float* __restrict__ h_out,        // [H]
              float* __restrict__ c_out)        // [H]
{
    const int j    = blockIdx.x;
    const int wave = threadIdx.x >> 6;
    const int lane = threadIdx.x & 63;
    const int row  = wave * LSTM_H + j;

    const float p      = part_l[row];
    const float c_in_j = c_in[j];

    float s = dot2048(W_ih + (size_t)row * LSTM_H, hx, lane);
    s = wave_reduce(s);

    __shared__ float gsh[4];
    if (lane == 0) gsh[wave] = s + p;
    __syncthreads();

    if (threadIdx.x == 0) {
        const float i_ = sigmoidf_(gsh[0]);
        const float f_ = sigmoidf_(gsh[1]);
        const float g_ = tanhf(gsh[2]);
        const float o_ = sigmoidf_(gsh[3]);
        const float c  = f_ * c_in_j + i_ * g_;
        c_out[j] = c;
        h_out[j] = o_ * tanhf(c);
    }
}

// ---------------- FC: decoded = fc_W @ h3 + fc_b (round-5 proven) -----------
__global__ __launch_bounds__(256)
void kfc(const float* __restrict__ fc_W,   // [E, H]
         const float* __restrict__ fc_b,   // [E]
         const float* __restrict__ h,      // [H]
         float* __restrict__ out)          // [E]
{
    const int wave = threadIdx.x >> 6;
    const int lane = threadIdx.x & 63;
    const int r = blockIdx.x * 4 + wave;

    const float b = fc_b[r];
    float s = dot2048(fc_W + (size_t)r * LSTM_H, h, lane);
    s = wave_reduce(s);
    if (lane == 0) out[r] = s + b;
}

extern "C" void kernel_launch(void* const* d_in, const int* in_sizes, int n_in,
                              void* d_out, int out_size, void* d_ws, size_t ws_size,
                              hipStream_t stream) {
    const int*   token  = (const int*)d_in[0];
    const float* hidden = (const float*)d_in[1];
    const float* cell   = (const float*)d_in[2];
    const float* emb    = (const float*)d_in[3];
    const float* W_ih0  = (const float*)d_in[4];
    const float* W_ihR  = (const float*)d_in[5];
    const float* W_hh   = (const float*)d_in[6];
    const float* b_ih   = (const float*)d_in[7];
    const float* b_hh   = (const float*)d_in[8];
    const float* fc_W   = (const float*)d_in[9];
    const float* fc_b   = (const float*)d_in[10];

    float* out     = (float*)d_out;
    float* decoded = out;                              // [E]
    float* h_new   = out + LSTM_E;                     // [L*H]
    float* c_new   = out + LSTM_E + LSTM_L * LSTM_H;   // [L*H]
    float* part    = (float*)d_ws;                     // [3][4H] = 96 KB

    const size_t WIH_STRIDE = (size_t)FOURH * LSTM_H;
    const size_t P_STRIDE   = (size_t)FOURH;

    // K1: layer-0 full + all W_hh partials; row-mode 2 rows/wave;
    //     W_hh nt except the 16MB cached slice.
    k1_parallel<<<5120, 256, 0, stream>>>(
        token, hidden, cell, emb, W_ih0, W_hh, b_ih, b_hh,
        h_new, c_new, part);

    // Sequential chain: layers 1..3 (67 MB each, cached reads -> L3 target).
    for (int l = 1; l < LSTM_L; ++l) {
        kb_layer<<<LSTM_H, 256, 0, stream>>>(
            W_ihR + (size_t)(l - 1) * WIH_STRIDE,
            part  + (size_t)(l - 1) * P_STRIDE,
            h_new + (size_t)(l - 1) * LSTM_H,
            cell  + (size_t)l * LSTM_H,
            h_new + (size_t)l * LSTM_H,
            c_new + (size_t)l * LSTM_H);
    }

    // FC (8.4 MB, cached).
    kfc<<<LSTM_E / 4, 256, 0, stream>>>(
        fc_W, fc_b, h_new + (size_t)(LSTM_L - 1) * LSTM_H, decoded);
}

// Round 11
// 85.799 us; speedup vs baseline: 1.0324x; 1.0324x over previous
//
#include <hip/hip_runtime.h>
#include <math.h>

// Problem constants: V=50257, H=2048, E=1024, L=4
#define LSTM_H 2048
#define LSTM_E 1024
#define LSTM_L 4
#define FOURH  8192

// Native clang vector type so __builtin_nontemporal_load accepts it.
typedef float f32x4 __attribute__((ext_vector_type(4)));

__device__ __forceinline__ float sigmoidf_(float x) {
    return 1.0f / (1.0f + __expf(-x));
}

__device__ __forceinline__ float wave_reduce(float s) {
    #pragma unroll
    for (int off = 32; off > 0; off >>= 1)
        s += __shfl_down(s, off, 64);
    return s;
}

// Regular cached dot (weights expected to be L3-resident across replays).
__device__ __forceinline__ float dot2048(const float* __restrict__ w,
                                         const float* __restrict__ v, int lane) {
    const float4* __restrict__ w4 = (const float4*)w;
    const float4* __restrict__ v4 = (const float4*)v;
    float s = 0.0f;
    #pragma unroll
    for (int t = 0; t < 8; ++t) {
        const int idx = lane + t * 64;
        float4 a = w4[idx];
        float4 b = v4[idx];
        s += a.x * b.x + a.y * b.y + a.z * b.z + a.w * b.w;
    }
    return s;
}

__device__ __forceinline__ float dot1024(const float* __restrict__ w,
                                         const float* __restrict__ v, int lane) {
    const float4* __restrict__ w4 = (const float4*)w;
    const float4* __restrict__ v4 = (const float4*)v;
    float s = 0.0f;
    #pragma unroll
    for (int t = 0; t < 4; ++t) {
        const int idx = lane + t * 64;
        float4 a = w4[idx];
        float4 b = v4[idx];
        s += a.x * b.x + a.y * b.y + a.z * b.z + a.w * b.w;
    }
    return s;
}

// Non-temporal weight stream (bulk of W_hh: single-use per replay; keep OUT of
// L3 so W_ih0/W_ihR/fc_W + a 16MB slice of W_hh stay LLC-resident).
__device__ __forceinline__ float dot2048_wnt(const float* __restrict__ w,
                                             const float* __restrict__ v, int lane) {
    const f32x4*  __restrict__ w4 = (const f32x4*)w;
    const float4* __restrict__ v4 = (const float4*)v;
    float s = 0.0f;
    #pragma unroll
    for (int t = 0; t < 8; ++t) {
        const int idx = lane + t * 64;
        f32x4  a = __builtin_nontemporal_load(w4 + idx);
        float4 b = v4[idx];
        s += a.x * b.x + a.y * b.y + a.z * b.z + a.w * b.w;
    }
    return s;
}

// ---------------- K1: all dependency-free work (round-9 = best measured) ----
// Blocks [0, 2048): unit-mode layer 0 — full gates + cell update for unit j.
//   W_ih0 row cached (L3-pinned set), W_hh0 row non-temporal.
// Blocks [2048, 8192): row-mode W_hh partials for layers 1..3 (1 row/wave,
//   block = 4 consecutive rows = 32KB). W_hh rows non-temporal EXCEPT the
//   last 2048 rows (16MB) which stay cached -> L3-resident across replays.
__global__ __launch_bounds__(256)
void k1_parallel(const int*   __restrict__ token,
                 const float* __restrict__ hidden,  // [L,1,H]
                 const float* __restrict__ cell,    // [L,1,H]
                 const float* __restrict__ emb,     // [V,E]
                 const float* __restrict__ W_ih0,   // [4H,E]
                 const float* __restrict__ W_hh,    // [L,4H,H]
                 const float* __restrict__ b_ih,    // [L,4H]
                 const float* __restrict__ b_hh,    // [L,4H]
                 float* __restrict__ h_new,         // [L*H]
                 float* __restrict__ c_new,         // [L*H]
                 float* __restrict__ part)          // [3][4H]
{
    const int wave = threadIdx.x >> 6;
    const int lane = threadIdx.x & 63;

    if (blockIdx.x < 2048) {
        // ---- unit-mode: layer 0, unit j ----
        const int j   = blockIdx.x;
        const int row = wave * LSTM_H + j;

        const float bias  = b_ih[row] + b_hh[row];
        const float c_in0 = cell[j];
        const float* xemb = emb + (size_t)(*token) * LSTM_E;

        float s = dot1024(W_ih0 + (size_t)row * LSTM_E, xemb, lane)
                + dot2048_wnt(W_hh + (size_t)row * LSTM_H, hidden, lane);
        s = wave_reduce(s);

        __shared__ float gsh[4];
        if (lane == 0) gsh[wave] = s + bias;
        __syncthreads();

        if (threadIdx.x == 0) {
            const float i_ = sigmoidf_(gsh[0]);
            const float f_ = sigmoidf_(gsh[1]);
            const float g_ = tanhf(gsh[2]);
            const float o_ = sigmoidf_(gsh[3]);
            const float c  = f_ * c_in0 + i_ * g_;
            c_new[j] = c;
            h_new[j] = o_ * tanhf(c);
        }
    } else {
        // ---- row-mode: W_hh partial for layers 1..3 (1 row per wave) ----
        const int r     = (blockIdx.x - 2048) * 4 + wave;   // 0..24575
        const int lidx  = r >> 13;          // 0..2  -> layer lidx+1
        const int rowin = r & (FOURH - 1);  // row within the layer's [4H]

        const size_t brow = (size_t)(lidx + 1) * FOURH + rowin;
        const float bias = b_ih[brow] + b_hh[brow];

        const float* w = W_hh + (size_t)(lidx + 1) * FOURH * LSTM_H
                               + (size_t)rowin * LSTM_H;
        const float* v = hidden + (size_t)(lidx + 1) * LSTM_H;

        // Last 2048 rows (16MB) of the 24576-row range stay CACHED: they join
        // the L3-resident set and skip HBM on subsequent replays.
        const bool cached = (r >= 24576 - 2048);
        float s = cached ? dot2048(w, v, lane) : dot2048_wnt(w, v, lane);
        s = wave_reduce(s);
        if (lane == 0) part[r] = s + bias;
    }
}

// ---------------- KB: sequential part of layer l (round-5 proven) ----------
// W_ihR reads stay CACHED — this is the stream we want L3-resident.
__global__ __launch_bounds__(256)
void kb_layer(const float* __restrict__ W_ih,   // [4H, H] (layer's W_ihR slice)
              const float* __restrict__ part_l, // [4H] W_hh part + biases
              const float* __restrict__ hx,     // [H] h_{l-1}
              const float* __restrict__ c_in,   // [H]
              float* __restrict__ h_out,        // [H]
              float* __restrict__ c_out)        // [H]
{
    const int j    = blockIdx.x;
    const int wave = threadIdx.x >> 6;
    const int lane = threadIdx.x & 63;
    const int row  = wave * LSTM_H + j;

    const float p      = part_l[row];
    const float c_in_j = c_in[j];

    float s = dot2048(W_ih + (size_t)row * LSTM_H, hx, lane);
    s = wave_reduce(s);

    __shared__ float gsh[4];
    if (lane == 0) gsh[wave] = s + p;
    __syncthreads();

    if (threadIdx.x == 0) {
        const float i_ = sigmoidf_(gsh[0]);
        const float f_ = sigmoidf_(gsh[1]);
        const float g_ = tanhf(gsh[2]);
        const float o_ = sigmoidf_(gsh[3]);
        const float c  = f_ * c_in_j + i_ * g_;
        c_out[j] = c;
        h_out[j] = o_ * tanhf(c);
    }
}

// ---------------- FC: decoded = fc_W @ h3 + fc_b (round-5 proven) -----------
__global__ __launch_bounds__(256)
void kfc(const float* __restrict__ fc_W,   // [E, H]
         const float* __restrict__ fc_b,   // [E]
         const float* __restrict__ h,      // [H]
         float* __restrict__ out)          // [E]
{
    const int wave = threadIdx.x >> 6;
    const int lane = threadIdx.x & 63;
    const int r = blockIdx.x * 4 + wave;

    const float b = fc_b[r];
    float s = dot2048(fc_W + (size_t)r * LSTM_H, h, lane);
    s = wave_reduce(s);
    if (lane == 0) out[r] = s + b;
}

extern "C" void kernel_launch(void* const* d_in, const int* in_sizes, int n_in,
                              void* d_out, int out_size, void* d_ws, size_t ws_size,
                              hipStream_t stream) {
    const int*   token  = (const int*)d_in[0];
    const float* hidden = (const float*)d_in[1];
    const float* cell   = (const float*)d_in[2];
    const float* emb    = (const float*)d_in[3];
    const float* W_ih0  = (const float*)d_in[4];
    const float* W_ihR  = (const float*)d_in[5];
    const float* W_hh   = (const float*)d_in[6];
    const float* b_ih   = (const float*)d_in[7];
    const float* b_hh   = (const float*)d_in[8];
    const float* fc_W   = (const float*)d_in[9];
    const float* fc_b   = (const float*)d_in[10];

    float* out     = (float*)d_out;
    float* decoded = out;                              // [E]
    float* h_new   = out + LSTM_E;                     // [L*H]
    float* c_new   = out + LSTM_E + LSTM_L * LSTM_H;   // [L*H]
    float* part    = (float*)d_ws;                     // [3][4H] = 96 KB

    const size_t WIH_STRIDE = (size_t)FOURH * LSTM_H;
    const size_t P_STRIDE   = (size_t)FOURH;

    // K1: layer-0 full + all W_hh partials; W_hh nt except 16MB cached slice.
    k1_parallel<<<8192, 256, 0, stream>>>(
        token, hidden, cell, emb, W_ih0, W_hh, b_ih, b_hh,
        h_new, c_new, part);

    // Sequential chain: layers 1..3 (67 MB each, cached reads -> L3 target).
    for (int l = 1; l < LSTM_L; ++l) {
        kb_layer<<<LSTM_H, 256, 0, stream>>>(
            W_ihR + (size_t)(l - 1) * WIH_STRIDE,
            part  + (size_t)(l - 1) * P_STRIDE,
            h_new + (size_t)(l - 1) * LSTM_H,
            cell  + (size_t)l * LSTM_H,
            h_new + (size_t)l * LSTM_H,
            c_new + (size_t)l * LSTM_H);
    }

    // FC (8.4 MB, cached).
    kfc<<<LSTM_E / 4, 256, 0, stream>>>(
        fc_W, fc_b, h_new + (size_t)(LSTM_L - 1) * LSTM_H, decoded);
}